// Round 4
// baseline (26952.911 us; speedup 1.0000x reference)
//
#include <hip/hip_runtime.h>
#include <cmath>

// Problem constants
#define Bc   64
#define Sc   512
#define Dc   256
#define Hc   512
#define OUTc 128

// Kernel config
#define NWG  256   // 128 layer0 + 128 layer1 workgroups, all resident (1/CU)
#define NTHR 512   // 8 waves
#define NL0  128
#define JPW  4
#define NROW 16
#define KP   1028  // padded LDS weight row stride

#define HBUF (Bc * Hc)             // 32768 floats per h buffer
#define H1_OFF 1024                // float offset (flags live in bytes [0,1024))
#define H2_OFF (1024 + 2 * HBUF)
#define WS_BYTES ((H2_OFF + 2 * HBUF) * 4)

#define QF 8192                    // quarter = 128 k = 8192 floats = 32 KB

// ---- coherent accessors: relaxed agent-scope atomics (sc1), no cache flushes ----
__device__ __forceinline__ float2 cload2(const float* p) {
    unsigned long long u = __hip_atomic_load((const unsigned long long*)p,
                                             __ATOMIC_RELAXED, __HIP_MEMORY_SCOPE_AGENT);
    union { unsigned long long u; float2 f; } c; c.u = u; return c.f;
}
__device__ __forceinline__ void cstore1(float* p, float v) {
    union { float f; unsigned u; } c; c.f = v;
    __hip_atomic_store((unsigned*)p, c.u, __ATOMIC_RELAXED, __HIP_MEMORY_SCOPE_AGENT);
}

// per-WG monotonic step flags; 64 lanes cover 128 producer flags
__device__ __forceinline__ void wait_layer(const unsigned* flags, unsigned target, int lane) {
    const unsigned* p = flags + lane;
    for (;;) {
        unsigned f0 = __hip_atomic_load(p,      __ATOMIC_RELAXED, __HIP_MEMORY_SCOPE_AGENT);
        unsigned f1 = __hip_atomic_load(p + 64, __ATOMIC_RELAXED, __HIP_MEMORY_SCOPE_AGENT);
        if (__all((f0 >= target) && (f1 >= target))) return;
        __builtin_amdgcn_s_sleep(1);
    }
}

__device__ __forceinline__ float sigmoidf_fast(float v) {
    return 1.0f / (1.0f + __expf(-v));
}

extern "C" __global__ void __launch_bounds__(NTHR)
lstm_persist(const float* __restrict__ x,
             const float* __restrict__ Wih0, const float* __restrict__ Whh0,
             const float* __restrict__ bih0, const float* __restrict__ bhh0,
             const float* __restrict__ Wih1, const float* __restrict__ Whh1,
             const float* __restrict__ bih1, const float* __restrict__ bhh1,
             const float* __restrict__ fcw, const float* __restrict__ fcb,
             float* __restrict__ out, float* __restrict__ wsf)
{
    __shared__ float Wl[NROW * KP];      // 64.3 KB weights, resident
    __shared__ float HST[2][QF];         // 64 KB h staging (ping-pong quarters)
    __shared__ float red[4 * Bc * 20];   // 20 KB reduction slabs

    unsigned* flags0 = (unsigned*)wsf;
    unsigned* flags1 = flags0 + 128;
    float* h1b = wsf + H1_OFF;           // [2][HBUF] transposed-chunked: h[k/2][b][2]
    float* h2b = wsf + H2_OFF;

    const int wg  = blockIdx.x;
    const int tid = threadIdx.x;
    const bool isL1 = (wg >= NL0);
    const int j0 = (isL1 ? wg - NL0 : wg) * JPW;
    const int K  = isL1 ? 1024 : 768;
    const int KD = isL1 ? 512  : 256;

    // ---- one-time weight staging ----
    {
        const float* Wi = isL1 ? Wih1 : Wih0;
        const float* Wh = isL1 ? Whh1 : Whh0;
        for (int r = 0; r < NROW; ++r) {
            const int g = r >> 2, jj = r & 3;
            const int row = g * Hc + j0 + jj;
            for (int c = tid; c < K; c += NTHR)
                Wl[r * KP + c] = (c < KD) ? Wi[row * KD + c] : Wh[row * Hc + (c - KD)];
        }
    }
    __syncthreads();

    const int w     = tid >> 6;
    const int lane  = tid & 63;
    const int bgrp  = lane & 15;
    const int rbase = (lane >> 4) << 2;
    const int w8    = w * 8;
    const int NCI   = KD >> 6;           // x-phase chunks for L0 (=4)

    const float* wr0 = &Wl[(rbase + 0) * KP];
    const float* wr1 = &Wl[(rbase + 1) * KP];
    const float* wr2 = &Wl[(rbase + 2) * KP];
    const float* wr3 = &Wl[(rbase + 3) * KP];

    // cell mapping: tid<256 -> (b = tid>>2, jj = tid&3)
    const int cb  = tid >> 2;
    const int cjj = tid & 3;
    const int hoff = ((j0 >> 1) + (cjj >> 1)) * 128 + cb * 2 + (cjj & 1);
    float cstate = 0.0f;
    float bias4[4];
    {
        const float* bi = isL1 ? bih1 : bih0;
        const float* bh = isL1 ? bhh1 : bhh0;
#pragma unroll
        for (int g = 0; g < 4; ++g)
            bias4[g] = bi[g * Hc + j0 + cjj] + bh[g * Hc + j0 + cjj];
    }

    unsigned* myflag = isL1 ? (flags1 + (wg - NL0)) : (flags0 + wg);

    for (int s = 0; s < Sc; ++s) {
        float acc[4][4];
#pragma unroll
        for (int i = 0; i < 4; ++i)
#pragma unroll
            for (int j = 0; j < 4; ++j) acc[i][j] = 0.0f;

        // FMA of one 8-k chunk: weights (LDS, broadcast) x h (LDS quarter, broadcast)
        auto fma_chunk = [&](const float* hq, int c2l, int wk) {
            const float4 wa0 = *(const float4*)(wr0 + wk), wb0 = *(const float4*)(wr0 + wk + 4);
            const float4 wa1 = *(const float4*)(wr1 + wk), wb1 = *(const float4*)(wr1 + wk + 4);
            const float4 wa2 = *(const float4*)(wr2 + wk), wb2 = *(const float4*)(wr2 + wk + 4);
            const float4 wa3 = *(const float4*)(wr3 + wk), wb3 = *(const float4*)(wr3 + wk + 4);
#pragma unroll
            for (int bb = 0; bb < 4; ++bb) {
                const float* hp = hq + c2l * 128 + (bgrp + 16 * bb) * 2;
                const float2 p0 = *(const float2*)(hp + 0 * 128);
                const float2 p1 = *(const float2*)(hp + 1 * 128);
                const float2 p2 = *(const float2*)(hp + 2 * 128);
                const float2 p3 = *(const float2*)(hp + 3 * 128);
                acc[bb][0] += wa0.x*p0.x + wa0.y*p0.y + wa0.z*p1.x + wa0.w*p1.y
                            + wb0.x*p2.x + wb0.y*p2.y + wb0.z*p3.x + wb0.w*p3.y;
                acc[bb][1] += wa1.x*p0.x + wa1.y*p0.y + wa1.z*p1.x + wa1.w*p1.y
                            + wb1.x*p2.x + wb1.y*p2.y + wb1.z*p3.x + wb1.w*p3.y;
                acc[bb][2] += wa2.x*p0.x + wa2.y*p0.y + wa2.z*p1.x + wa2.w*p1.y
                            + wb2.x*p2.x + wb2.y*p2.y + wb2.z*p3.x + wb2.w*p3.y;
                acc[bb][3] += wa3.x*p0.x + wa3.y*p0.y + wa3.z*p1.x + wa3.w*p1.y
                            + wb3.x*p2.x + wb3.y*p2.y + wb3.z*p3.x + wb3.w*p3.y;
            }
        };

        // staged 512-k phase: 4 quarters, ping-pong LDS, next-quarter global loads
        // held in registers under the current quarter's compute
        auto phase_staged = [&](const float* gsrc, int wkoff) {
#pragma unroll
            for (int i = 0; i < 8; ++i) {
                const int off = (tid + i * NTHR) * 2;
                *(float2*)(&HST[0][0] + off) = cload2(gsrc + off);
            }
            __syncthreads();
            for (int q = 0; q < 4; ++q) {
                const float* cur = &HST[q & 1][0];
                float* nxt = &HST[(q + 1) & 1][0];
                float2 stg[8];
                const bool more = (q + 1 < 4);
                if (more) {
                    const float* gq = gsrc + (size_t)(q + 1) * QF;
#pragma unroll
                    for (int i = 0; i < 8; ++i)
                        stg[i] = cload2(gq + (tid + i * NTHR) * 2);
                }
                fma_chunk(cur, (w8) >> 1,      wkoff + q * 128 + w8);
                fma_chunk(cur, (64 + w8) >> 1, wkoff + q * 128 + 64 + w8);
                if (more) {
#pragma unroll
                    for (int i = 0; i < 8; ++i)
                        *(float2*)(nxt + (tid + i * NTHR) * 2) = stg[i];
                }
                __syncthreads();
            }
        };

        auto gate = [&](const unsigned* f, unsigned t) {
            if (w == 0) wait_layer(f, t, lane);
            __syncthreads();
        };

        if (!isL1) {
            // x-contribution: dependency-free, register-streamed (x read-only, L2-cached)
            {
                const float* xb[4];
#pragma unroll
                for (int bb = 0; bb < 4; ++bb)
                    xb[bb] = x + (size_t)(bgrp + 16 * bb) * Sc * Dc + (size_t)s * Dc;
                float4 va[4], vb[4], na[4], nb[4];
                auto ldx = [&](int c, float4* A, float4* Bv) {
                    const int kc = c * 64 + w8;
#pragma unroll
                    for (int bb = 0; bb < 4; ++bb) {
                        A[bb]  = *(const float4*)(xb[bb] + kc);
                        Bv[bb] = *(const float4*)(xb[bb] + kc + 4);
                    }
                };
                ldx(0, va, vb);
                for (int c = 0; c < NCI; ++c) {
                    if (c + 1 < NCI) ldx(c + 1, na, nb);
                    const int kc = c * 64 + w8;
                    const float4 wa0 = *(const float4*)(wr0 + kc), wb0 = *(const float4*)(wr0 + kc + 4);
                    const float4 wa1 = *(const float4*)(wr1 + kc), wb1 = *(const float4*)(wr1 + kc + 4);
                    const float4 wa2 = *(const float4*)(wr2 + kc), wb2 = *(const float4*)(wr2 + kc + 4);
                    const float4 wa3 = *(const float4*)(wr3 + kc), wb3 = *(const float4*)(wr3 + kc + 4);
#pragma unroll
                    for (int bb = 0; bb < 4; ++bb) {
                        const float4 a = va[bb], b = vb[bb];
                        acc[bb][0] += wa0.x*a.x + wa0.y*a.y + wa0.z*a.z + wa0.w*a.w
                                    + wb0.x*b.x + wb0.y*b.y + wb0.z*b.z + wb0.w*b.w;
                        acc[bb][1] += wa1.x*a.x + wa1.y*a.y + wa1.z*a.z + wa1.w*a.w
                                    + wb1.x*b.x + wb1.y*b.y + wb1.z*b.z + wb1.w*b.w;
                        acc[bb][2] += wa2.x*a.x + wa2.y*a.y + wa2.z*a.z + wa2.w*a.w
                                    + wb2.x*b.x + wb2.y*b.y + wb2.z*b.z + wb2.w*b.w;
                        acc[bb][3] += wa3.x*a.x + wa3.y*a.y + wa3.z*a.z + wa3.w*a.w
                                    + wb3.x*b.x + wb3.y*b.y + wb3.z*b.z + wb3.w*b.w;
                    }
                    if (c + 1 < NCI) {
#pragma unroll
                        for (int bb = 0; bb < 4; ++bb) { va[bb] = na[bb]; vb[bb] = nb[bb]; }
                    }
                }
            }
            if (w == 0) {
                wait_layer(flags0, (unsigned)s, lane);                  // h1[s-1] ready
                wait_layer(flags1, (unsigned)(s > 0 ? s - 1 : 0), lane);// WAR vs L1
            }
            __syncthreads();
            phase_staged(h1b + (size_t)((s + 1) & 1) * HBUF, 256);      // recurrent, cols 256..767
        } else {
            gate(flags1, (unsigned)s);                                  // h2[s-1] ready (+WAR)
            phase_staged(h2b + (size_t)((s + 1) & 1) * HBUF, 512);      // own recurrent, cols 512..1023
            gate(flags0, (unsigned)(s + 1));                            // h1[s] ready (tight edge)
            phase_staged(h1b + (size_t)(s & 1) * HBUF, 0);              // input part, cols 0..511
        }

        // cross-wave K reduction
        if (w >= 4) {
#pragma unroll
            for (int bb = 0; bb < 4; ++bb) {
                const int b = bgrp + 16 * bb;
                *(float4*)&red[((w - 4) * Bc + b) * 20 + rbase] =
                    make_float4(acc[bb][0], acc[bb][1], acc[bb][2], acc[bb][3]);
            }
        }
        __syncthreads();
        if (w < 4) {
#pragma unroll
            for (int bb = 0; bb < 4; ++bb) {
                const int b = bgrp + 16 * bb;
                float4 p = *(float4*)&red[(w * Bc + b) * 20 + rbase];
                p.x += acc[bb][0]; p.y += acc[bb][1]; p.z += acc[bb][2]; p.w += acc[bb][3];
                *(float4*)&red[(w * Bc + b) * 20 + rbase] = p;
            }
        }
        __syncthreads();

        if (tid < 256) {
            float gv[4];
#pragma unroll
            for (int g = 0; g < 4; ++g) {
                const int r = g * 4 + cjj;
                gv[g] = red[(0 * Bc + cb) * 20 + r] + red[(1 * Bc + cb) * 20 + r]
                      + red[(2 * Bc + cb) * 20 + r] + red[(3 * Bc + cb) * 20 + r] + bias4[g];
            }
            const float ig = sigmoidf_fast(gv[0]);
            const float fg = sigmoidf_fast(gv[1]);
            const float gg = tanhf(gv[2]);
            const float og = sigmoidf_fast(gv[3]);
            cstate = fg * cstate + ig * gg;
            const float hv = og * tanhf(cstate);
            float* hb = (isL1 ? h2b : h1b) + (size_t)(s & 1) * HBUF;
            cstore1(hb + hoff, hv);
        }
        __syncthreads();   // drains h stores (vmcnt(0)) before publish
        if (tid == 0)
            __hip_atomic_store(myflag, (unsigned)(s + 1), __ATOMIC_RELAXED, __HIP_MEMORY_SCOPE_AGENT);
    }

    // ---- FC epilogue: WG b in [0,64) ----
    if (wg < Bc) {
        if (w == 0) wait_layer(flags1, (unsigned)Sc, lane);
        __syncthreads();
        const int b = wg;
        const float* h2 = h2b + (size_t)((Sc - 1) & 1) * HBUF;
        const int o = tid & 127, q = tid >> 7;
        const float* wrow = fcw + (size_t)o * Hc;
        float a = 0.0f;
        for (int k = q * 128; k < q * 128 + 128; k += 2) {
            const float2 hv = cload2(h2 + (size_t)(k >> 1) * 128 + b * 2);
            a += hv.x * wrow[k] + hv.y * wrow[k + 1];
        }
        __syncthreads();
        red[q * 128 + o] = a;
        __syncthreads();
        if (tid < OUTc)
            out[b * OUTc + tid] = red[tid] + red[128 + tid] + red[256 + tid] + red[384 + tid] + fcb[tid];
    }
}

extern "C" void kernel_launch(void* const* d_in, const int* in_sizes, int n_in,
                              void* d_out, int out_size, void* d_ws, size_t ws_size,
                              hipStream_t stream) {
    const float* x    = (const float*)d_in[0];
    const float* Wih0 = (const float*)d_in[1];
    const float* Whh0 = (const float*)d_in[2];
    const float* bih0 = (const float*)d_in[3];
    const float* bhh0 = (const float*)d_in[4];
    const float* Wih1 = (const float*)d_in[5];
    const float* Whh1 = (const float*)d_in[6];
    const float* bih1 = (const float*)d_in[7];
    const float* bhh1 = (const float*)d_in[8];
    const float* fcw  = (const float*)d_in[9];
    const float* fcb  = (const float*)d_in[10];
    float* out = (float*)d_out;
    float* wsf = (float*)d_ws;

    hipMemsetAsync(d_ws, 0, WS_BYTES, stream);

    lstm_persist<<<dim3(NWG), dim3(NTHR), 0, stream>>>(
        x, Wih0, Whh0, bih0, bhh0, Wih1, Whh1, bih1, bhh1, fcw, fcb, out, wsf);
}

// Round 5
// 11108.565 us; speedup vs baseline: 2.4263x; 2.4263x over previous
//
#include <hip/hip_runtime.h>
#include <cmath>

// Problem constants
#define Bc   64
#define Sc   512
#define Dc   256
#define Hc   512
#define OUTc 128

// Kernel config
#define NWG  256   // 128 layer0 + 128 layer1 workgroups, all resident (1/CU)
#define NTHR 512   // 8 waves
#define NL0  128
#define JPW  4
#define NROW 16
#define KP   1028  // padded LDS weight row stride

// Flags: ONE per 128B cache line (stride 32 u32) -> poll load spreads over 128
// MALL lines instead of 2 (r2/r3 had all waves hammering 2 lines = MALL bank
// saturation theory). Flag region: 2*128*32*4 B = 32 KB.
#define FSTR 32
#define H1_OFF 8192                 // float offset of h1 buffers (after 32 KB flag region)
#define HBUF (Bc * Hc)              // 32768 floats per h buffer
#define H2_OFF (H1_OFF + 2 * HBUF)
#define WS_BYTES ((H2_OFF + 2 * HBUF) * 4)

// ---- coherent accessors: relaxed agent-scope atomics (sc1), no cache flushes ----
__device__ __forceinline__ float2 cload2(const float* p) {
    unsigned long long u = __hip_atomic_load((const unsigned long long*)p,
                                             __ATOMIC_RELAXED, __HIP_MEMORY_SCOPE_AGENT);
    union { unsigned long long u; float2 f; } c; c.u = u; return c.f;
}
__device__ __forceinline__ void cstore1(float* p, float v) {
    union { float f; unsigned u; } c; c.f = v;
    __hip_atomic_store((unsigned*)p, c.u, __ATOMIC_RELAXED, __HIP_MEMORY_SCOPE_AGENT);
}

// per-WG monotonic step flags, line-padded; ONLY wave 0 of a WG calls this.
__device__ __forceinline__ void wait_layer(const unsigned* flags, unsigned target, int lane) {
    const unsigned* p0 = flags + (size_t)lane * FSTR;
    const unsigned* p1 = flags + (size_t)(lane + 64) * FSTR;
    for (;;) {
        unsigned f0 = __hip_atomic_load(p0, __ATOMIC_RELAXED, __HIP_MEMORY_SCOPE_AGENT);
        unsigned f1 = __hip_atomic_load(p1, __ATOMIC_RELAXED, __HIP_MEMORY_SCOPE_AGENT);
        if (__all((f0 >= target) && (f1 >= target))) return;
        __builtin_amdgcn_s_sleep(16);   // ~1k cyc backoff: cheap vs step time, kind to MALL
    }
}

__device__ __forceinline__ float sigmoidf_fast(float v) {
    return 1.0f / (1.0f + __expf(-v));
}

extern "C" __global__ void __launch_bounds__(NTHR)
lstm_persist(const float* __restrict__ x,
             const float* __restrict__ Wih0, const float* __restrict__ Whh0,
             const float* __restrict__ bih0, const float* __restrict__ bhh0,
             const float* __restrict__ Wih1, const float* __restrict__ Whh1,
             const float* __restrict__ bih1, const float* __restrict__ bhh1,
             const float* __restrict__ fcw, const float* __restrict__ fcb,
             float* __restrict__ out, float* __restrict__ wsf)
{
    __shared__ float Wl[NROW * KP];
    __shared__ float red[4 * Bc * 20];

    unsigned* flags0 = (unsigned*)wsf;            // 128 flags, one per 128B line
    unsigned* flags1 = flags0 + 128 * FSTR;
    float* h1b = wsf + H1_OFF;                    // [2][HBUF] transposed-chunked h[k/2][b][2]
    float* h2b = wsf + H2_OFF;

    const int wg  = blockIdx.x;
    const int tid = threadIdx.x;
    const bool isL1 = (wg >= NL0);
    const int j0 = (isL1 ? wg - NL0 : wg) * JPW;
    const int K  = isL1 ? 1024 : 768;
    const int KD = isL1 ? 512  : 256;

    // ---- one-time weight staging ----
    {
        const float* Wi = isL1 ? Wih1 : Wih0;
        const float* Wh = isL1 ? Whh1 : Whh0;
        for (int r = 0; r < NROW; ++r) {
            const int g = r >> 2, jj = r & 3;
            const int row = g * Hc + j0 + jj;
            for (int c = tid; c < K; c += NTHR)
                Wl[r * KP + c] = (c < KD) ? Wi[row * KD + c] : Wh[row * Hc + (c - KD)];
        }
    }
    __syncthreads();

    const int w     = tid >> 6;
    const int lane  = tid & 63;
    const int bgrp  = lane & 15;
    const int rbase = (lane >> 4) << 2;
    const int NC    = K >> 6;    // chunks per wave: 12 / 16
    const int NCI   = KD >> 6;   // input-part chunks: 4 / 8

    const float* wr0 = &Wl[(rbase + 0) * KP];
    const float* wr1 = &Wl[(rbase + 1) * KP];
    const float* wr2 = &Wl[(rbase + 2) * KP];
    const float* wr3 = &Wl[(rbase + 3) * KP];

    // cell mapping: tid<256 -> (b = tid>>2, jj = tid&3)
    const int cb  = tid >> 2;
    const int cjj = tid & 3;
    const int hoff = ((j0 >> 1) + (cjj >> 1)) * 128 + cb * 2 + (cjj & 1);
    float cstate = 0.0f;
    float bias4[4];
    {
        const float* bi = isL1 ? bih1 : bih0;
        const float* bh = isL1 ? bhh1 : bhh0;
#pragma unroll
        for (int g = 0; g < 4; ++g)
            bias4[g] = bi[g * Hc + j0 + cjj] + bh[g * Hc + j0 + cjj];
    }

    unsigned* myflag = (isL1 ? flags1 + (size_t)(wg - NL0) * FSTR
                             : flags0 + (size_t)wg * FSTR);

    for (int s = 0; s < Sc; ++s) {
        float acc[4][4];
#pragma unroll
        for (int i = 0; i < 4; ++i)
#pragma unroll
            for (int j = 0; j < 4; ++j) acc[i][j] = 0.0f;

        auto fma_block = [&](int kc, const float4* A, const float4* Bv) {
            const float4 wa0 = *(const float4*)(wr0 + kc), wb0 = *(const float4*)(wr0 + kc + 4);
            const float4 wa1 = *(const float4*)(wr1 + kc), wb1 = *(const float4*)(wr1 + kc + 4);
            const float4 wa2 = *(const float4*)(wr2 + kc), wb2 = *(const float4*)(wr2 + kc + 4);
            const float4 wa3 = *(const float4*)(wr3 + kc), wb3 = *(const float4*)(wr3 + kc + 4);
#pragma unroll
            for (int bb = 0; bb < 4; ++bb) {
                const float4 a = A[bb], b = Bv[bb];
                acc[bb][0] += wa0.x*a.x + wa0.y*a.y + wa0.z*a.z + wa0.w*a.w
                            + wb0.x*b.x + wb0.y*b.y + wb0.z*b.z + wb0.w*b.w;
                acc[bb][1] += wa1.x*a.x + wa1.y*a.y + wa1.z*a.z + wa1.w*a.w
                            + wb1.x*b.x + wb1.y*b.y + wb1.z*b.z + wb1.w*b.w;
                acc[bb][2] += wa2.x*a.x + wa2.y*a.y + wa2.z*a.z + wa2.w*a.w
                            + wb2.x*b.x + wb2.y*b.y + wb2.z*b.z + wb2.w*b.w;
                acc[bb][3] += wa3.x*a.x + wa3.y*a.y + wa3.z*a.z + wa3.w*a.w
                            + wb3.x*b.x + wb3.y*b.y + wb3.z*b.z + wb3.w*b.w;
            }
        };

        // recurrent/h phase over chunk range (r3 pattern: per-lane sparse sc1
        // gather, distance-1 chunk prefetch — MALL-friendly, 0.7 GB HBM measured)
        auto phase_h = [&](int cbeg, int cend, int sub, const float* hb_) {
            const float* hbb[4];
#pragma unroll
            for (int bb = 0; bb < 4; ++bb) hbb[bb] = hb_ + (bgrp + 16 * bb) * 2;
            auto ld = [&](int c, float4* A, float4* Bv) {
                const int c2 = (c * 64 + w * 8 - sub) >> 1;
#pragma unroll
                for (int bb = 0; bb < 4; ++bb) {
                    float2 p0 = cload2(hbb[bb] + (size_t)(c2 + 0) * 128);
                    float2 p1 = cload2(hbb[bb] + (size_t)(c2 + 1) * 128);
                    float2 p2 = cload2(hbb[bb] + (size_t)(c2 + 2) * 128);
                    float2 p3 = cload2(hbb[bb] + (size_t)(c2 + 3) * 128);
                    A[bb]  = make_float4(p0.x, p0.y, p1.x, p1.y);
                    Bv[bb] = make_float4(p2.x, p2.y, p3.x, p3.y);
                }
            };
            float4 va[4], vb[4], na[4], nb[4];
            ld(cbeg, va, vb);
            for (int c = cbeg; c < cend; ++c) {
                if (c + 1 < cend) ld(c + 1, na, nb);
                fma_block(c * 64 + w * 8, va, vb);
                if (c + 1 < cend) {
#pragma unroll
                    for (int bb = 0; bb < 4; ++bb) { va[bb] = na[bb]; vb[bb] = nb[bb]; }
                }
            }
        };

        const float* h1rd = h1b + (size_t)((s + (isL1 ? 0 : 1)) & 1) * HBUF;

        if (!isL1) {
            // x-contribution: dependency-free, overlaps producers finishing
            {
                const float* xb[4];
#pragma unroll
                for (int bb = 0; bb < 4; ++bb)
                    xb[bb] = x + (size_t)(bgrp + 16 * bb) * Sc * Dc + (size_t)s * Dc;
                float4 va[4], vb[4], na[4], nb[4];
                auto ldx = [&](int c, float4* A, float4* Bv) {
                    const int kc = c * 64 + w * 8;
#pragma unroll
                    for (int bb = 0; bb < 4; ++bb) {
                        A[bb]  = *(const float4*)(xb[bb] + kc);
                        Bv[bb] = *(const float4*)(xb[bb] + kc + 4);
                    }
                };
                ldx(0, va, vb);
                for (int c = 0; c < NCI; ++c) {
                    if (c + 1 < NCI) ldx(c + 1, na, nb);
                    fma_block(c * 64 + w * 8, va, vb);
                    if (c + 1 < NCI) {
#pragma unroll
                        for (int bb = 0; bb < 4; ++bb) { va[bb] = na[bb]; vb[bb] = nb[bb]; }
                    }
                }
            }
            if (w == 0) {
                wait_layer(flags0, (unsigned)s, lane);                   // h1[s-1] ready
                wait_layer(flags1, (unsigned)(s > 0 ? s - 1 : 0), lane); // WAR vs L1
            }
            __syncthreads();
            phase_h(NCI, NC, KD, h1rd);
        } else {
            if (w == 0) wait_layer(flags1, (unsigned)s, lane);           // h2[s-1] ready (+WAR)
            __syncthreads();
            const float* h2rd = h2b + (size_t)((s + 1) & 1) * HBUF;
            phase_h(NCI, NC, KD, h2rd);      // own-layer recurrent half first
            if (w == 0) wait_layer(flags0, (unsigned)(s + 1), lane);     // h1[s] ready (tight edge)
            __syncthreads();
            phase_h(0, NCI, 0, h1rd);
        }

        // cross-wave K reduction
        if (w >= 4) {
#pragma unroll
            for (int bb = 0; bb < 4; ++bb) {
                const int b = bgrp + 16 * bb;
                *(float4*)&red[((w - 4) * Bc + b) * 20 + rbase] =
                    make_float4(acc[bb][0], acc[bb][1], acc[bb][2], acc[bb][3]);
            }
        }
        __syncthreads();
        if (w < 4) {
#pragma unroll
            for (int bb = 0; bb < 4; ++bb) {
                const int b = bgrp + 16 * bb;
                float4 p = *(float4*)&red[(w * Bc + b) * 20 + rbase];
                p.x += acc[bb][0]; p.y += acc[bb][1]; p.z += acc[bb][2]; p.w += acc[bb][3];
                *(float4*)&red[(w * Bc + b) * 20 + rbase] = p;
            }
        }
        __syncthreads();

        if (tid < 256) {
            float gv[4];
#pragma unroll
            for (int g = 0; g < 4; ++g) {
                const int r = g * 4 + cjj;
                gv[g] = red[(0 * Bc + cb) * 20 + r] + red[(1 * Bc + cb) * 20 + r]
                      + red[(2 * Bc + cb) * 20 + r] + red[(3 * Bc + cb) * 20 + r] + bias4[g];
            }
            const float ig = sigmoidf_fast(gv[0]);
            const float fg = sigmoidf_fast(gv[1]);
            const float gg = tanhf(gv[2]);
            const float og = sigmoidf_fast(gv[3]);
            cstate = fg * cstate + ig * gg;
            const float hv = og * tanhf(cstate);
            float* hb = (isL1 ? h2b : h1b) + (size_t)(s & 1) * HBUF;
            cstore1(hb + hoff, hv);
        }
        __syncthreads();   // drains h stores (vmcnt(0)) before publish
        if (tid == 0)
            __hip_atomic_store(myflag, (unsigned)(s + 1), __ATOMIC_RELAXED, __HIP_MEMORY_SCOPE_AGENT);
    }

    // ---- FC epilogue: WG b in [0,64) ----
    if (wg < Bc) {
        if (w == 0) wait_layer(flags1, (unsigned)Sc, lane);
        __syncthreads();
        const int b = wg;
        const float* h2 = h2b + (size_t)((Sc - 1) & 1) * HBUF;
        const int o = tid & 127, q = tid >> 7;
        const float* wrow = fcw + (size_t)o * Hc;
        float a = 0.0f;
        for (int k = q * 128; k < q * 128 + 128; k += 2) {
            const float2 hv = cload2(h2 + (size_t)(k >> 1) * 128 + b * 2);
            a += hv.x * wrow[k] + hv.y * wrow[k + 1];
        }
        __syncthreads();
        red[q * 128 + o] = a;
        __syncthreads();
        if (tid < OUTc)
            out[b * OUTc + tid] = red[tid] + red[128 + tid] + red[256 + tid] + red[384 + tid] + fcb[tid];
    }
}

extern "C" void kernel_launch(void* const* d_in, const int* in_sizes, int n_in,
                              void* d_out, int out_size, void* d_ws, size_t ws_size,
                              hipStream_t stream) {
    const float* x    = (const float*)d_in[0];
    const float* Wih0 = (const float*)d_in[1];
    const float* Whh0 = (const float*)d_in[2];
    const float* bih0 = (const float*)d_in[3];
    const float* bhh0 = (const float*)d_in[4];
    const float* Wih1 = (const float*)d_in[5];
    const float* Whh1 = (const float*)d_in[6];
    const float* bih1 = (const float*)d_in[7];
    const float* bhh1 = (const float*)d_in[8];
    const float* fcw  = (const float*)d_in[9];
    const float* fcb  = (const float*)d_in[10];
    float* out = (float*)d_out;
    float* wsf = (float*)d_ws;

    hipMemsetAsync(d_ws, 0, WS_BYTES, stream);

    lstm_persist<<<dim3(NWG), dim3(NTHR), 0, stream>>>(
        x, Wih0, Whh0, bih0, bhh0, Wih1, Whh1, bih1, bhh1, fcw, fcb, out, wsf);
}